// Round 5
// baseline (190.845 us; speedup 1.0000x reference)
//
#include <hip/hip_runtime.h>
#include <hip/hip_bf16.h>

#define BB 8
#define NN 2048
#define VV 256
#define HH 1024
#define CHK 64
#define RPC 32
constexpr float EPS = 1e-5f;

typedef __attribute__((ext_vector_type(4))) float floatx4;
typedef __attribute__((ext_vector_type(8))) short short8;

__device__ __forceinline__ void load_lds16(const void* g, void* l) {
    __builtin_amdgcn_global_load_lds((const __attribute__((address_space(1))) void*)g,
                                     (__attribute__((address_space(3))) void*)l, 16, 0, 0);
}
__device__ __forceinline__ float bf16s_to_f(short s) {
    unsigned u = ((unsigned)(unsigned short)s) << 16;
    return __builtin_bit_cast(float, u);
}

// ---------------------------------------------------------------------------
// K1: per-batch LayerNorms of row 0 (attn + mlp), sum0[b]=attn_row0 . qk_dir,
//     and v_bos = wo_w @ wv_bos  (block 8)
// ---------------------------------------------------------------------------
__global__ void prep_kernel(const float* __restrict__ h,
                            const float* __restrict__ g_attn, const float* __restrict__ b_attn,
                            const float* __restrict__ g_mlp,  const float* __restrict__ b_mlp,
                            const float* __restrict__ qk_dir,
                            const float* __restrict__ wo_w,  const float* __restrict__ wv_bos,
                            float* __restrict__ attn_row0, float* __restrict__ mlp_row0,
                            float* __restrict__ v_bos, float* __restrict__ sum0)
{
    int t = threadIdx.x;
    __shared__ float red[VV];
    if (blockIdx.x < BB) {
        int b = blockIdx.x;
        float x = h[(size_t)b * NN * VV + t];
        red[t] = x; __syncthreads();
        for (int s = 128; s > 0; s >>= 1) { if (t < s) red[t] += red[t + s]; __syncthreads(); }
        float m = red[0] * (1.0f / VV); __syncthreads();
        float xc = x - m;
        red[t] = xc * xc; __syncthreads();
        for (int s = 128; s > 0; s >>= 1) { if (t < s) red[t] += red[t + s]; __syncthreads(); }
        float var = red[0] * (1.0f / VV); __syncthreads();
        float inv = 1.0f / sqrtf(var + EPS);
        float an = xc * inv * g_attn[t] + b_attn[t];
        float mn = xc * inv * g_mlp[t] + b_mlp[t];
        attn_row0[b * VV + t] = an;
        mlp_row0[b * VV + t]  = mn;
        red[t] = an * qk_dir[t]; __syncthreads();
        for (int s = 128; s > 0; s >>= 1) { if (t < s) red[t] += red[t + s]; __syncthreads(); }
        if (t == 0) sum0[b] = red[0];
    } else {
        const float4* wp = reinterpret_cast<const float4*>(wo_w + (size_t)t * VV);
        const float4* vp = reinterpret_cast<const float4*>(wv_bos);
        float acc = 0.f;
        for (int j = 0; j < VV / 4; ++j) {
            float4 a = wp[j], b = vp[j];
            acc += a.x * b.x + a.y * b.y + a.z * b.z + a.w * b.w;
        }
        v_bos[t] = acc;
    }
}

// ---------------------------------------------------------------------------
// K2: fused pass over h: bf16 convert (BOS row swap), softmax weights, and
//     scan chunk partials. vsum uses the bf16-ROUNDED values so the prefix
//     sum is consistent with attn_kernel's bf16 reads of Xb.
// ---------------------------------------------------------------------------
__global__ __launch_bounds__(256) void scan_qkw_cvt_kernel(
    const float* __restrict__ h, const float* __restrict__ mlp_row0,
    const float* __restrict__ wv,
    const float* __restrict__ qk_bos, const float* __restrict__ qk_prev,
    const float* __restrict__ sum0,
    short* __restrict__ Xb,
    float* __restrict__ w0, float* __restrict__ wprev, float* __restrict__ wz,
    float* __restrict__ chunkSum)
{
    __shared__ float lds[4][VV];
    int wave = threadIdx.x >> 6, lane = threadIdx.x & 63;
    int b = blockIdx.x / CHK, c = blockIdx.x % CHK;
    int r0 = c * RPC + wave * 8;
    float4 wv4 = reinterpret_cast<const float4*>(wv)[lane];
    float4 qb4 = reinterpret_cast<const float4*>(qk_bos)[lane];
    float4 qp4 = reinterpret_cast<const float4*>(qk_prev)[lane];
    float s0b = sum0[b];
    float4 vsum = {0.f, 0.f, 0.f, 0.f};
#pragma unroll
    for (int rr = 0; rr < 8; ++rr) {
        int r = r0 + rr;
        size_t base = ((size_t)b * NN + r) * VV;
        float4 x = *reinterpret_cast<const float4*>(h + base + lane * 4);
        float4 xs = x;
        if (r == 0) xs = *reinterpret_cast<const float4*>(mlp_row0 + b * VV + lane * 4);
        __hip_bfloat16 c0 = __float2bfloat16(xs.x), c1 = __float2bfloat16(xs.y),
                       c2 = __float2bfloat16(xs.z), c3 = __float2bfloat16(xs.w);
        short4 pk;
        pk.x = *reinterpret_cast<short*>(&c0);
        pk.y = *reinterpret_cast<short*>(&c1);
        pk.z = *reinterpret_cast<short*>(&c2);
        pk.w = *reinterpret_cast<short*>(&c3);
        *reinterpret_cast<short4*>(Xb + base + lane * 4) = pk;
        if (r != 0) {
            // rounded values (consistent with attn_kernel reading Xb)
            vsum.x += bf16s_to_f(pk.x) * wv4.x; vsum.y += bf16s_to_f(pk.y) * wv4.y;
            vsum.z += bf16s_to_f(pk.z) * wv4.z; vsum.w += bf16s_to_f(pk.w) * wv4.w;
        }
        float s1 = x.x * qb4.x + x.y * qb4.y + x.z * qb4.z + x.w * qb4.w;
        float s2 = x.x * qp4.x + x.y * qp4.y + x.z * qp4.z + x.w * qp4.w;
        for (int off = 32; off > 0; off >>= 1) {
            s1 += __shfl_down(s1, off);
            s2 += __shfl_down(s2, off);
        }
        if (lane == 0) {
            int gid = b * NN + r;
            float W0, WP, WZ;
            if (r == 0) { W0 = 1.f; WP = 0.f; WZ = 0.f; }
            else if (r == 1) {
                float a = s1 * s0b + s2;
                float m = fmaxf(a, 0.f);
                float ea = expf(a - m), ez = expf(-m);
                float Z = ea + ez;
                W0 = ea / Z; WZ = ez / Z; WP = WZ;
            } else {
                float a = s1 * s0b;
                float m = fmaxf(fmaxf(a, s2), 0.f);
                float ea = expf(a - m), ed = expf(s2 - m), ez = expf(-m);
                float Z = ea + ed + (float)(r - 1) * ez;
                W0 = ea / Z; WP = ed / Z; WZ = ez / Z;
            }
            w0[gid] = W0; wprev[gid] = WP; wz[gid] = WZ;
        }
    }
    reinterpret_cast<float4*>(lds[wave])[lane] = vsum;
    __syncthreads();
    int v = threadIdx.x;
    chunkSum[((size_t)b * CHK + c) * VV + v] = lds[0][v] + lds[1][v] + lds[2][v] + lds[3][v];
}

// K3: exclusive scan of chunk partials — all 64 loaded up-front (one latency)
__global__ void chunkscan_kernel(float* __restrict__ chunkSum)
{
    int b = blockIdx.x, v = threadIdx.x;
    float vals[CHK];
#pragma unroll
    for (int c = 0; c < CHK; ++c) vals[c] = chunkSum[(b * CHK + c) * VV + v];
    float run = 0.f;
#pragma unroll
    for (int c = 0; c < CHK; ++c) { float t = vals[c]; vals[c] = run; run += t; }
#pragma unroll
    for (int c = 0; c < CHK; ++c) chunkSum[(b * CHK + c) * VV + v] = vals[c];
}

// K4: attention emit — reads bf16 Xb (half the traffic of fp32 h).
//     128 threads, each owns 2 adjacent v-columns (float2/short2 vector ops).
__global__ __launch_bounds__(128) void attn_kernel(
    const short* __restrict__ Xb, const float* __restrict__ wv,
    const float* __restrict__ v_bos,
    const float* __restrict__ w0, const float* __restrict__ wprev,
    const float* __restrict__ wz, const float* __restrict__ chunkSum,
    float* __restrict__ out)
{
    int b = blockIdx.x / CHK, c = blockIdx.x % CHK;
    int v = threadIdx.x * 2;
    float2 wv2 = *reinterpret_cast<const float2*>(wv + v);
    float2 vb2 = *reinterpret_cast<const float2*>(v_bos + v);
    float2 S = *reinterpret_cast<const float2*>(chunkSum + (b * CHK + c) * VV + v);
    int r0 = c * RPC;
    float2 prev = {0.f, 0.f};
    if (r0 > 0) {
        short2 p = *reinterpret_cast<const short2*>(Xb + ((size_t)b * NN + r0 - 1) * VV + v);
        prev.x = bf16s_to_f(p.x) * wv2.x; prev.y = bf16s_to_f(p.y) * wv2.y;
    }
    for (int r = r0; r < r0 + RPC; ++r) {
        size_t idx = ((size_t)b * NN + r) * VV + v;
        float2 o;
        if (r == 0) {
            o = vb2;
            prev.x = 0.f; prev.y = 0.f;
        } else {
            short2 xv = *reinterpret_cast<const short2*>(Xb + idx);
            float2 val;
            val.x = bf16s_to_f(xv.x) * wv2.x; val.y = bf16s_to_f(xv.y) * wv2.y;
            S.x += val.x; S.y += val.y;
            int wi = b * NN + r;
            float W0 = w0[wi], WD = wprev[wi] - wz[wi], WZ = wz[wi];
            o.x = W0 * vb2.x + WD * prev.x + WZ * S.x;
            o.y = W0 * vb2.y + WD * prev.y + WZ * S.y;
            prev = val;
        }
        *reinterpret_cast<float2*>(out + idx) = o;
    }
}

__global__ void cvt_w_kernel(const float* __restrict__ w1, const float* __restrict__ w2,
                             __hip_bfloat16* __restrict__ w1b, __hip_bfloat16* __restrict__ w2b)
{
    int i = (blockIdx.x * blockDim.x + threadIdx.x) * 4;
    const float* src;
    __hip_bfloat16* dst;
    if (i < HH * VV) { src = w1 + i; dst = w1b + i; }
    else             { src = w2 + (i - HH * VV); dst = w2b + (i - HH * VV); }
    float4 x = *reinterpret_cast<const float4*>(src);
    dst[0] = __float2bfloat16(x.x);
    dst[1] = __float2bfloat16(x.y);
    dst[2] = __float2bfloat16(x.z);
    dst[3] = __float2bfloat16(x.w);
}

// ---------------------------------------------------------------------------
// K5: fused MLP v2  out += relu(X @ w1^T) @ w2^T
//   grid 256 (1/CU), 256 thr (4 waves). M-tile 64. X A-frags REGISTER-resident
//   (128 VGPRs, loaded once). Loop H in 8 chunks of 128:
//     stage sW1[128x256] (async, 64 KB) + sW2[256x128] (VGPR path, 64 KB)
//     GEMM1: wave computes Y[64 x 32] (its h-col stripe), 16-shape, A-from-regs
//     relu -> bf16 -> sY[64x128]
//     GEMM2: wave tile 64x64 (MI=4,NJ=4 -> 0.047 LDS B/MAC), accumulate oacc
//   3 barriers/hc x 8 hc. LDS = 144 KB.
// ---------------------------------------------------------------------------
__global__ __launch_bounds__(256) void mlp_fused2(const short* __restrict__ Xb,
                                                  const short* __restrict__ w1b,
                                                  const short* __restrict__ w2b,
                                                  float* __restrict__ out)
{
    __shared__ __align__(16) short sW1[128 * 256];  // 64 KB  [h-row][k]
    __shared__ __align__(16) short sW2[256 * 128];  // 64 KB  [v-col][h-k]
    __shared__ __align__(16) short sY[64 * 128];    // 16 KB  [row][h-col]
    int wave = threadIdx.x >> 6, lane = threadIdx.x & 63;
    int ra = lane & 15, q = lane >> 4;
    int m0 = blockIdx.x * 64;

    // ---- X fragments: xf[ks][i] = A[m0 + i*16 + ra][ks*32 + q*8 ..+8] ----
    short8 xf[8][4];
#pragma unroll
    for (int ks = 0; ks < 8; ++ks)
#pragma unroll
        for (int i = 0; i < 4; ++i)
            xf[ks][i] = *reinterpret_cast<const short8*>(
                Xb + (size_t)(m0 + i * 16 + ra) * VV + ks * 32 + q * 8);

    floatx4 oacc[4][4];
#pragma unroll
    for (int i = 0; i < 4; ++i)
#pragma unroll
        for (int j = 0; j < 4; ++j) oacc[i][j] = floatx4{0.f, 0.f, 0.f, 0.f};

    // ---- staging helper (hc chunk) ----
    auto stage = [&](int hc) {
        // sW1: 64 async instructions; inst g covers rows g*2,g*2+1 (contiguous 1 KB)
#pragma unroll
        for (int it = 0; it < 16; ++it) {
            int g = wave * 16 + it;
            load_lds16(w1b + ((size_t)(hc * 128 + g * 2) * VV) + lane * 8, sW1 + g * 512);
        }
        // sW2: VGPR path: 4 v-rows x 128 shorts per iteration per wave
#pragma unroll
        for (int it = 0; it < 16; ++it) {
            int v4 = wave * 64 + it * 4 + (lane >> 4);
            short8 t = *reinterpret_cast<const short8*>(
                w2b + (size_t)v4 * HH + hc * 128 + (lane & 15) * 8);
            *reinterpret_cast<short8*>(sW2 + v4 * 128 + (lane & 15) * 8) = t;
        }
    };

    stage(0);
    for (int hc = 0; hc < 8; ++hc) {
        __syncthreads();   // staging visible
        // ---- GEMM1: Y stripe 64 rows x 32 h-cols (h = wave*32 ..) ----
        floatx4 yacc[4][2];
#pragma unroll
        for (int i = 0; i < 4; ++i) { yacc[i][0] = floatx4{0,0,0,0}; yacc[i][1] = floatx4{0,0,0,0}; }
#pragma unroll
        for (int ks = 0; ks < 8; ++ks) {
#pragma unroll
            for (int j = 0; j < 2; ++j) {
                int n = wave * 32 + j * 16 + ra;
                short8 bfr = *reinterpret_cast<const short8*>(sW1 + n * 256 + ks * 32 + q * 8);
#pragma unroll
                for (int i = 0; i < 4; ++i)
                    yacc[i][j] = __builtin_amdgcn_mfma_f32_16x16x32_bf16(xf[ks][i], bfr, yacc[i][j], 0, 0, 0);
            }
        }
        // relu -> bf16 -> sY
#pragma unroll
        for (int i = 0; i < 4; ++i)
#pragma unroll
            for (int j = 0; j < 2; ++j)
#pragma unroll
                for (int reg = 0; reg < 4; ++reg) {
                    int row = i * 16 + q * 4 + reg;
                    int col = wave * 32 + j * 16 + ra;
                    __hip_bfloat16 hb = __float2bfloat16(fmaxf(yacc[i][j][reg], 0.f));
                    sY[row * 128 + col] = *reinterpret_cast<short*>(&hb);
                }
        __syncthreads();   // sY ready (and sW1 fully consumed)

        // ---- GEMM2: oacc[64x64 per wave] += Yc @ w2c^T ----
#pragma unroll
        for (int kk = 0; kk < 4; ++kk) {
            short8 a2[4];
#pragma unroll
            for (int i = 0; i < 4; ++i)
                a2[i] = *reinterpret_cast<const short8*>(sY + (i * 16 + ra) * 128 + kk * 32 + q * 8);
#pragma unroll
            for (int j = 0; j < 4; ++j) {
                int n = wave * 64 + j * 16 + ra;
                short8 b2 = *reinterpret_cast<const short8*>(sW2 + n * 128 + kk * 32 + q * 8);
#pragma unroll
                for (int i = 0; i < 4; ++i)
                    oacc[i][j] = __builtin_amdgcn_mfma_f32_16x16x32_bf16(a2[i], b2, oacc[i][j], 0, 0, 0);
            }
        }
        __syncthreads();   // sW2/sY consumed; safe to restage
        if (hc < 7) stage(hc + 1);
    }

    // ---- epilogue: out += oacc ----
#pragma unroll
    for (int i = 0; i < 4; ++i)
#pragma unroll
        for (int j = 0; j < 4; ++j)
#pragma unroll
            for (int reg = 0; reg < 4; ++reg) {
                int row = m0 + i * 16 + q * 4 + reg;
                int col = wave * 64 + j * 16 + ra;
                out[(size_t)row * VV + col] += oacc[i][j][reg];
            }
}

// ---------------------------------------------------------------------------
extern "C" void kernel_launch(void* const* d_in, const int* in_sizes, int n_in,
                              void* d_out, int out_size, void* d_ws, size_t ws_size,
                              hipStream_t stream)
{
    const float* h        = (const float*)d_in[0];
    const float* ln_attn_g = (const float*)d_in[3];
    const float* ln_attn_b = (const float*)d_in[4];
    const float* ln_mlp_g  = (const float*)d_in[5];
    const float* ln_mlp_b  = (const float*)d_in[6];
    const float* wv        = (const float*)d_in[7];
    const float* wv_bos    = (const float*)d_in[8];
    const float* wo_w      = (const float*)d_in[9];
    const float* qk_bos    = (const float*)d_in[10];
    const float* qk_prev   = (const float*)d_in[11];
    const float* qk_dir    = (const float*)d_in[12];
    const float* w1        = (const float*)d_in[13];
    const float* w2        = (const float*)d_in[14];
    float* out = (float*)d_out;

    float* attn_row0 = (float*)d_ws;                 // 2048
    float* mlp_row0  = attn_row0 + BB * VV;          // 2048
    float* v_bos     = mlp_row0 + BB * VV;           // 256
    float* sum0      = v_bos + VV;                   // 8
    float* w0        = sum0 + 8;                     // 16384
    float* wprev     = w0 + BB * NN;                 // 16384
    float* wzz       = wprev + BB * NN;              // 16384
    float* chunkSum  = wzz + BB * NN;                // BB*CHK*VV = 131072
    short* Xb            = (short*)(chunkSum + BB * CHK * VV);
    __hip_bfloat16* w1b  = (__hip_bfloat16*)(Xb + (size_t)BB * NN * VV);
    __hip_bfloat16* w2b  = w1b + HH * VV;

    prep_kernel<<<BB + 1, 256, 0, stream>>>(h, ln_attn_g, ln_attn_b, ln_mlp_g, ln_mlp_b,
                                            qk_dir, wo_w, wv_bos,
                                            attn_row0, mlp_row0, v_bos, sum0);
    cvt_w_kernel<<<(2 * HH * VV / 4) / 256, 256, 0, stream>>>(w1, w2, w1b, w2b);
    scan_qkw_cvt_kernel<<<BB * CHK, 256, 0, stream>>>(h, mlp_row0, wv, qk_bos, qk_prev,
                                                      sum0, Xb, w0, wprev, wzz, chunkSum);
    chunkscan_kernel<<<BB, 256, 0, stream>>>(chunkSum);
    attn_kernel<<<BB * CHK, 128, 0, stream>>>(Xb, wv, v_bos, w0, wprev, wzz, chunkSum, out);
    mlp_fused2<<<256, 256, 0, stream>>>(Xb, (const short*)w1b, (const short*)w2b, out);
}

// Round 6
// 172.273 us; speedup vs baseline: 1.1078x; 1.1078x over previous
//
#include <hip/hip_runtime.h>
#include <hip/hip_bf16.h>

#define BB 8
#define NN 2048
#define VV 256
#define HH 1024
#define CHK 64
#define RPC 32
constexpr float EPS = 1e-5f;

typedef __attribute__((ext_vector_type(4))) float floatx4;
typedef __attribute__((ext_vector_type(8))) short short8;

__device__ __forceinline__ void load_lds16(const void* g, void* l) {
    __builtin_amdgcn_global_load_lds((const __attribute__((address_space(1))) void*)g,
                                     (__attribute__((address_space(3))) void*)l, 16, 0, 0);
}
__device__ __forceinline__ float bf16s_to_f(short s) {
    unsigned u = ((unsigned)(unsigned short)s) << 16;
    return __builtin_bit_cast(float, u);
}

// ---------------------------------------------------------------------------
// K1: per-batch LayerNorms of row 0 (attn + mlp), sum0[b]=attn_row0 . qk_dir,
//     and v_bos = wo_w @ wv_bos  (block 8)
// ---------------------------------------------------------------------------
__global__ void prep_kernel(const float* __restrict__ h,
                            const float* __restrict__ g_attn, const float* __restrict__ b_attn,
                            const float* __restrict__ g_mlp,  const float* __restrict__ b_mlp,
                            const float* __restrict__ qk_dir,
                            const float* __restrict__ wo_w,  const float* __restrict__ wv_bos,
                            float* __restrict__ attn_row0, float* __restrict__ mlp_row0,
                            float* __restrict__ v_bos, float* __restrict__ sum0)
{
    int t = threadIdx.x;
    __shared__ float red[VV];
    if (blockIdx.x < BB) {
        int b = blockIdx.x;
        float x = h[(size_t)b * NN * VV + t];
        red[t] = x; __syncthreads();
        for (int s = 128; s > 0; s >>= 1) { if (t < s) red[t] += red[t + s]; __syncthreads(); }
        float m = red[0] * (1.0f / VV); __syncthreads();
        float xc = x - m;
        red[t] = xc * xc; __syncthreads();
        for (int s = 128; s > 0; s >>= 1) { if (t < s) red[t] += red[t + s]; __syncthreads(); }
        float var = red[0] * (1.0f / VV); __syncthreads();
        float inv = 1.0f / sqrtf(var + EPS);
        float an = xc * inv * g_attn[t] + b_attn[t];
        float mn = xc * inv * g_mlp[t] + b_mlp[t];
        attn_row0[b * VV + t] = an;
        mlp_row0[b * VV + t]  = mn;
        red[t] = an * qk_dir[t]; __syncthreads();
        for (int s = 128; s > 0; s >>= 1) { if (t < s) red[t] += red[t + s]; __syncthreads(); }
        if (t == 0) sum0[b] = red[0];
    } else {
        const float4* wp = reinterpret_cast<const float4*>(wo_w + (size_t)t * VV);
        const float4* vp = reinterpret_cast<const float4*>(wv_bos);
        float acc = 0.f;
        for (int j = 0; j < VV / 4; ++j) {
            float4 a = wp[j], b = vp[j];
            acc += a.x * b.x + a.y * b.y + a.z * b.z + a.w * b.w;
        }
        v_bos[t] = acc;
    }
}

// ---------------------------------------------------------------------------
// K2: fused pass over h: bf16 convert (BOS row swap), softmax weights, and
//     scan chunk partials (bf16-rounded for consistency with attn_kernel).
// ---------------------------------------------------------------------------
__global__ __launch_bounds__(256) void scan_qkw_cvt_kernel(
    const float* __restrict__ h, const float* __restrict__ mlp_row0,
    const float* __restrict__ wv,
    const float* __restrict__ qk_bos, const float* __restrict__ qk_prev,
    const float* __restrict__ sum0,
    short* __restrict__ Xb,
    float* __restrict__ w0, float* __restrict__ wprev, float* __restrict__ wz,
    float* __restrict__ chunkSum)
{
    __shared__ float lds[4][VV];
    int wave = threadIdx.x >> 6, lane = threadIdx.x & 63;
    int b = blockIdx.x / CHK, c = blockIdx.x % CHK;
    int r0 = c * RPC + wave * 8;
    float4 wv4 = reinterpret_cast<const float4*>(wv)[lane];
    float4 qb4 = reinterpret_cast<const float4*>(qk_bos)[lane];
    float4 qp4 = reinterpret_cast<const float4*>(qk_prev)[lane];
    float s0b = sum0[b];
    float4 vsum = {0.f, 0.f, 0.f, 0.f};
#pragma unroll
    for (int rr = 0; rr < 8; ++rr) {
        int r = r0 + rr;
        size_t base = ((size_t)b * NN + r) * VV;
        float4 x = *reinterpret_cast<const float4*>(h + base + lane * 4);
        float4 xs = x;
        if (r == 0) xs = *reinterpret_cast<const float4*>(mlp_row0 + b * VV + lane * 4);
        __hip_bfloat16 c0 = __float2bfloat16(xs.x), c1 = __float2bfloat16(xs.y),
                       c2 = __float2bfloat16(xs.z), c3 = __float2bfloat16(xs.w);
        short4 pk;
        pk.x = *reinterpret_cast<short*>(&c0);
        pk.y = *reinterpret_cast<short*>(&c1);
        pk.z = *reinterpret_cast<short*>(&c2);
        pk.w = *reinterpret_cast<short*>(&c3);
        *reinterpret_cast<short4*>(Xb + base + lane * 4) = pk;
        if (r != 0) {
            vsum.x += bf16s_to_f(pk.x) * wv4.x; vsum.y += bf16s_to_f(pk.y) * wv4.y;
            vsum.z += bf16s_to_f(pk.z) * wv4.z; vsum.w += bf16s_to_f(pk.w) * wv4.w;
        }
        float s1 = x.x * qb4.x + x.y * qb4.y + x.z * qb4.z + x.w * qb4.w;
        float s2 = x.x * qp4.x + x.y * qp4.y + x.z * qp4.z + x.w * qp4.w;
        for (int off = 32; off > 0; off >>= 1) {
            s1 += __shfl_down(s1, off);
            s2 += __shfl_down(s2, off);
        }
        if (lane == 0) {
            int gid = b * NN + r;
            float W0, WP, WZ;
            if (r == 0) { W0 = 1.f; WP = 0.f; WZ = 0.f; }
            else if (r == 1) {
                float a = s1 * s0b + s2;
                float m = fmaxf(a, 0.f);
                float ea = expf(a - m), ez = expf(-m);
                float Z = ea + ez;
                W0 = ea / Z; WZ = ez / Z; WP = WZ;
            } else {
                float a = s1 * s0b;
                float m = fmaxf(fmaxf(a, s2), 0.f);
                float ea = expf(a - m), ed = expf(s2 - m), ez = expf(-m);
                float Z = ea + ed + (float)(r - 1) * ez;
                W0 = ea / Z; WP = ed / Z; WZ = ez / Z;
            }
            w0[gid] = W0; wprev[gid] = WP; wz[gid] = WZ;
        }
    }
    reinterpret_cast<float4*>(lds[wave])[lane] = vsum;
    __syncthreads();
    int v = threadIdx.x;
    chunkSum[((size_t)b * CHK + c) * VV + v] = lds[0][v] + lds[1][v] + lds[2][v] + lds[3][v];
}

// K3: exclusive scan of chunk partials
__global__ void chunkscan_kernel(float* __restrict__ chunkSum)
{
    int b = blockIdx.x, v = threadIdx.x;
    float vals[CHK];
#pragma unroll
    for (int c = 0; c < CHK; ++c) vals[c] = chunkSum[(b * CHK + c) * VV + v];
    float run = 0.f;
#pragma unroll
    for (int c = 0; c < CHK; ++c) { float t = vals[c]; vals[c] = run; run += t; }
#pragma unroll
    for (int c = 0; c < CHK; ++c) chunkSum[(b * CHK + c) * VV + v] = vals[c];
}

// K4: attention emit — reads bf16 Xb
__global__ __launch_bounds__(128) void attn_kernel(
    const short* __restrict__ Xb, const float* __restrict__ wv,
    const float* __restrict__ v_bos,
    const float* __restrict__ w0, const float* __restrict__ wprev,
    const float* __restrict__ wz, const float* __restrict__ chunkSum,
    float* __restrict__ out)
{
    int b = blockIdx.x / CHK, c = blockIdx.x % CHK;
    int v = threadIdx.x * 2;
    float2 wv2 = *reinterpret_cast<const float2*>(wv + v);
    float2 vb2 = *reinterpret_cast<const float2*>(v_bos + v);
    float2 S = *reinterpret_cast<const float2*>(chunkSum + (b * CHK + c) * VV + v);
    int r0 = c * RPC;
    float2 prev = {0.f, 0.f};
    if (r0 > 0) {
        short2 p = *reinterpret_cast<const short2*>(Xb + ((size_t)b * NN + r0 - 1) * VV + v);
        prev.x = bf16s_to_f(p.x) * wv2.x; prev.y = bf16s_to_f(p.y) * wv2.y;
    }
    for (int r = r0; r < r0 + RPC; ++r) {
        size_t idx = ((size_t)b * NN + r) * VV + v;
        float2 o;
        if (r == 0) {
            o = vb2;
            prev.x = 0.f; prev.y = 0.f;
        } else {
            short2 xv = *reinterpret_cast<const short2*>(Xb + idx);
            float2 val;
            val.x = bf16s_to_f(xv.x) * wv2.x; val.y = bf16s_to_f(xv.y) * wv2.y;
            S.x += val.x; S.y += val.y;
            int wi = b * NN + r;
            float W0 = w0[wi], WD = wprev[wi] - wz[wi], WZ = wz[wi];
            o.x = W0 * vb2.x + WD * prev.x + WZ * S.x;
            o.y = W0 * vb2.y + WD * prev.y + WZ * S.y;
            prev = val;
        }
        *reinterpret_cast<float2*>(out + idx) = o;
    }
}

__global__ void cvt_w_kernel(const float* __restrict__ w1, const float* __restrict__ w2,
                             __hip_bfloat16* __restrict__ w1b, __hip_bfloat16* __restrict__ w2b)
{
    int i = (blockIdx.x * blockDim.x + threadIdx.x) * 4;
    const float* src;
    __hip_bfloat16* dst;
    if (i < HH * VV) { src = w1 + i; dst = w1b + i; }
    else             { src = w2 + (i - HH * VV); dst = w2b + (i - HH * VV); }
    float4 x = *reinterpret_cast<const float4*>(src);
    dst[0] = __float2bfloat16(x.x);
    dst[1] = __float2bfloat16(x.y);
    dst[2] = __float2bfloat16(x.z);
    dst[3] = __float2bfloat16(x.w);
}

// ---------------------------------------------------------------------------
// K5: fused MLP v3  out += relu(X @ w1^T) @ w2^T
//   grid 256 (1/CU), 512 thr = 8 waves (wm 2 x wn 4). M-tile 64.
//   X A-frags register-resident per wm-half (64 VGPR). H in 16 chunks of 64.
//   Double-buffered sW1/sW2 (DMA prefetch issued right after top barrier so
//   the compiler's vmcnt(0)-at-barrier only pays the remainder).
//   XOR seg-swizzle on all tiles: 16B segment s of row n stored at s^(n&7)
//   (R2-verified: zero bank conflicts). LDS = 2*32 + 2*32 + 8 = 136 KB.
//   GEMM1 wave tile 32x16 (A regs, 8 b128/hc); GEMM2 32x64 (12 b128/hc).
// ---------------------------------------------------------------------------
__global__ __launch_bounds__(512) void mlp_fused3(const short* __restrict__ Xb,
                                                  const short* __restrict__ w1b,
                                                  const short* __restrict__ w2b,
                                                  float* __restrict__ out)
{
    __shared__ __align__(16) short sW1[2][64 * 256];  // 2 x 32 KB [h-row][k]
    __shared__ __align__(16) short sW2[2][256 * 64];  // 2 x 32 KB [v-col][h-k]
    __shared__ __align__(16) short sY[64 * 64];       // 8 KB      [row][h-col]
    int wave = threadIdx.x >> 6, lane = threadIdx.x & 63;
    int wm = wave >> 2, wn = wave & 3;
    int ra = lane & 15, q = lane >> 4;
    int m0 = blockIdx.x * 64;

    // X fragments: rows of this wave's wm-half, full K=256
    short8 xf[8][2];
#pragma unroll
    for (int ks = 0; ks < 8; ++ks)
#pragma unroll
        for (int i = 0; i < 2; ++i)
            xf[ks][i] = *reinterpret_cast<const short8*>(
                Xb + (size_t)(m0 + wm * 32 + i * 16 + ra) * VV + ks * 32 + q * 8);

    floatx4 oacc[2][4];
#pragma unroll
    for (int i = 0; i < 2; ++i)
#pragma unroll
        for (int j = 0; j < 4; ++j) oacc[i][j] = floatx4{0.f, 0.f, 0.f, 0.f};

    auto stage = [&](int hc, int buf) {
        // sW1[buf]: 64 rows x 512 B; 32 DMA instr (2 rows each), 4 per wave
#pragma unroll
        for (int it = 0; it < 4; ++it) {
            int g = wave * 4 + it;
            int n = g * 2 + (lane >> 5);
            int slot = lane & 31;
            load_lds16(w1b + (size_t)(hc * 64 + n) * VV + (slot ^ (n & 7)) * 8,
                       &sW1[buf][g * 512]);
        }
        // sW2[buf]: 256 rows x 128 B; 32 DMA instr (8 rows each), 4 per wave
#pragma unroll
        for (int it = 0; it < 4; ++it) {
            int g = wave * 4 + it;
            int v = g * 8 + (lane >> 3);
            int slot = lane & 7;
            load_lds16(w2b + (size_t)v * HH + hc * 64 + (slot ^ (v & 7)) * 8,
                       &sW2[buf][g * 512]);
        }
    };

    stage(0, 0);
    for (int hc = 0; hc < 16; ++hc) {
        int p = hc & 1;
        __syncthreads();                 // buf[p] staged+visible; sY consumed
        if (hc < 15) stage(hc + 1, p ^ 1);   // async prefetch, consumed next iter

        // ---- GEMM1: Y[wm*32..+32][wn*16..+16] = X @ w1c^T ----
        floatx4 yacc[2];
        yacc[0] = floatx4{0.f, 0.f, 0.f, 0.f};
        yacc[1] = floatx4{0.f, 0.f, 0.f, 0.f};
        int nb = wn * 16 + ra;
#pragma unroll
        for (int ks = 0; ks < 8; ++ks) {
            short8 bfr = *reinterpret_cast<const short8*>(
                &sW1[p][nb * 256 + (((ks * 4 + q) ^ (ra & 7)) * 8)]);
#pragma unroll
            for (int i = 0; i < 2; ++i)
                yacc[i] = __builtin_amdgcn_mfma_f32_16x16x32_bf16(xf[ks][i], bfr, yacc[i], 0, 0, 0);
        }
        // relu -> bf16 -> sY (swizzled)
#pragma unroll
        for (int i = 0; i < 2; ++i)
#pragma unroll
            for (int reg = 0; reg < 4; ++reg) {
                int m = wm * 32 + i * 16 + q * 4 + reg;
                int ke = wn * 16 + ra;
                __hip_bfloat16 hb = __float2bfloat16(fmaxf(yacc[i][reg], 0.f));
                sY[m * 64 + (((ke >> 3) ^ (m & 7)) * 8) + (ke & 7)] =
                    *reinterpret_cast<short*>(&hb);
            }
        __syncthreads();                 // sY visible

        // ---- GEMM2: oacc[wm*32..+32][wn*64..+64] += Yc @ w2c^T ----
#pragma unroll
        for (int kk = 0; kk < 2; ++kk) {
            short8 a2[2];
#pragma unroll
            for (int i = 0; i < 2; ++i) {
                int m = wm * 32 + i * 16 + ra;
                a2[i] = *reinterpret_cast<const short8*>(
                    &sY[m * 64 + (((kk * 4 + q) ^ (ra & 7)) * 8)]);
            }
#pragma unroll
            for (int j = 0; j < 4; ++j) {
                int v = wn * 64 + j * 16 + ra;
                short8 b2 = *reinterpret_cast<const short8*>(
                    &sW2[p][v * 64 + (((kk * 4 + q) ^ (ra & 7)) * 8)]);
#pragma unroll
                for (int i = 0; i < 2; ++i)
                    oacc[i][j] = __builtin_amdgcn_mfma_f32_16x16x32_bf16(a2[i], b2, oacc[i][j], 0, 0, 0);
            }
        }
    }

    // ---- epilogue: out += oacc ----
#pragma unroll
    for (int i = 0; i < 2; ++i)
#pragma unroll
        for (int j = 0; j < 4; ++j)
#pragma unroll
            for (int reg = 0; reg < 4; ++reg) {
                int row = m0 + wm * 32 + i * 16 + q * 4 + reg;
                int col = wn * 64 + j * 16 + ra;
                out[(size_t)row * VV + col] += oacc[i][j][reg];
            }
}

// ---------------------------------------------------------------------------
extern "C" void kernel_launch(void* const* d_in, const int* in_sizes, int n_in,
                              void* d_out, int out_size, void* d_ws, size_t ws_size,
                              hipStream_t stream)
{
    const float* h        = (const float*)d_in[0];
    const float* ln_attn_g = (const float*)d_in[3];
    const float* ln_attn_b = (const float*)d_in[4];
    const float* ln_mlp_g  = (const float*)d_in[5];
    const float* ln_mlp_b  = (const float*)d_in[6];
    const float* wv        = (const float*)d_in[7];
    const float* wv_bos    = (const float*)d_in[8];
    const float* wo_w      = (const float*)d_in[9];
    const float* qk_bos    = (const float*)d_in[10];
    const float* qk_prev   = (const float*)d_in[11];
    const float* qk_dir    = (const float*)d_in[12];
    const float* w1        = (const float*)d_in[13];
    const float* w2        = (const float*)d_in[14];
    float* out = (float*)d_out;

    float* attn_row0 = (float*)d_ws;                 // 2048
    float* mlp_row0  = attn_row0 + BB * VV;          // 2048
    float* v_bos     = mlp_row0 + BB * VV;           // 256
    float* sum0      = v_bos + VV;                   // 8
    float* w0        = sum0 + 8;                     // 16384
    float* wprev     = w0 + BB * NN;                 // 16384
    float* wzz       = wprev + BB * NN;              // 16384
    float* chunkSum  = wzz + BB * NN;                // BB*CHK*VV = 131072
    short* Xb            = (short*)(chunkSum + BB * CHK * VV);
    __hip_bfloat16* w1b  = (__hip_bfloat16*)(Xb + (size_t)BB * NN * VV);
    __hip_bfloat16* w2b  = w1b + HH * VV;

    prep_kernel<<<BB + 1, 256, 0, stream>>>(h, ln_attn_g, ln_attn_b, ln_mlp_g, ln_mlp_b,
                                            qk_dir, wo_w, wv_bos,
                                            attn_row0, mlp_row0, v_bos, sum0);
    cvt_w_kernel<<<(2 * HH * VV / 4) / 256, 256, 0, stream>>>(w1, w2, w1b, w2b);
    scan_qkw_cvt_kernel<<<BB * CHK, 256, 0, stream>>>(h, mlp_row0, wv, qk_bos, qk_prev,
                                                      sum0, Xb, w0, wprev, wzz, chunkSum);
    chunkscan_kernel<<<BB, 256, 0, stream>>>(chunkSum);
    attn_kernel<<<BB * CHK, 128, 0, stream>>>(Xb, wv, v_bos, w0, wprev, wzz, chunkSum, out);
    mlp_fused3<<<256, 512, 0, stream>>>(Xb, (const short*)w1b, (const short*)w2b, out);
}